// Round 1
// baseline (9621.355 us; speedup 1.0000x reference)
//
#include <hip/hip_runtime.h>
#include <cstdint>
#include <cstddef>

typedef unsigned int uint;
typedef unsigned short ushort;
typedef unsigned long long u64;
typedef __attribute__((ext_vector_type(8))) __bf16 bf16x8;
typedef __attribute__((ext_vector_type(4))) __bf16 bf16x4v;
typedef __attribute__((ext_vector_type(4))) float floatx4;

#define WLD 6144      // weight row stride = 3*(D+H)

// ---- workspace layout (bytes). Row convention for xb/gates/htseq: r = t*32 + n (t-major).
static const size_t OFF_GATES = 0;              // bf16 16384x3072
static const size_t OFF_XB    = 100663296;      // bf16 16384x1024
static const size_t OFF_HTSEQ = 134217728;      // bf16 16384x1024
// whtg_t/whtc_t overlay the htseq region: consumed (into LDS) before any htseq write.
static const size_t OFF_WHTGT = OFF_HTSEQ;              // bf16 2048x1024
static const size_t OFF_WHTCT = OFF_HTSEQ + 4194304;    // bf16 1024x1024
static const size_t OFF_WXTT  = 167772160;      // bf16 3072x1024 (B^T)
// Tagged broadcast buffers overlay wxtt: wxtt is dead after gemm<0>, which runs
// before zero_tags + recur. ht tags: 16384 u64 (128KB), rh tags: 16384 u64.
static const size_t OFF_TAGS  = OFF_WXTT;       // u64[32768] = 256KB
static const size_t OFF_WHDT  = 174063616;      // bf16 3072x1024
static const size_t OFF_WXD1T = 180355072;      // bf16 2048x1024
static const size_t OFF_WXD2T = 184549376;      // bf16 1024x1024

__device__ __forceinline__ float sigmoidf_(float x) { return 1.f / (1.f + __expf(-x)); }
__device__ __forceinline__ float tanhf_(float x) { float e = __expf(2.f * x); return 1.f - 2.f / (e + 1.f); }

// agent-scope relaxed atomics: operate at LIC (device coherence point).
__device__ __forceinline__ u64 ald64(const u64* p) {
  return __hip_atomic_load(p, __ATOMIC_RELAXED, __HIP_MEMORY_SCOPE_AGENT);
}
__device__ __forceinline__ void ast64(u64* p, u64 v) {
  __hip_atomic_store(p, v, __ATOMIC_RELAXED, __HIP_MEMORY_SCOPE_AGENT);
}
// tagged word: hi32 = epoch, lo32 = two bf16 (low half = even col)
__device__ __forceinline__ u64 mk_tag(uint e, float ve, float vo) {
  union { __bf16 b; ushort u; } a, c; a.b = (__bf16)ve; c.b = (__bf16)vo;
  return ((u64)e << 32) | ((u64)c.u << 16) | (u64)a.u;
}

// ---------------- prep kernels ----------------

// x [n][t][1024] fp32 -> xb bf16 rows r=t*32+n.
__global__ __launch_bounds__(256) void convert_x(const float4* __restrict__ x4,
                                                 __bf16* __restrict__ xb) {
  const int s = blockIdx.x;              // source row n*512+t
  const int n = s >> 9, t = s & 511;
  const int d = (t << 5) | n;            // dest row t*32+n
  float4 v = x4[(size_t)s * 256 + threadIdx.x];
  bf16x4v o = { (__bf16)v.x, (__bf16)v.y, (__bf16)v.z, (__bf16)v.w };
  *reinterpret_cast<bf16x4v*>(xb + (size_t)d * 1024 + threadIdx.x * 4) = o;
}

// zero both tagged broadcast buffers (32768 u64) at the coherence point.
// Must run after gemm<0> (tags overlay wxtt) and before recur.
__global__ __launch_bounds__(256) void zero_tags(u64* __restrict__ t) {
  ast64(t + (size_t)blockIdx.x * 256 + threadIdx.x, 0ull);
}

// src: fp32 block, row stride WLD, 1024 rows (k), gridDim.x*32 cols. dst: bf16 [c][k].
__global__ __launch_bounds__(256) void transpose_conv(const float* __restrict__ src,
                                                      __bf16* __restrict__ dst) {
  __shared__ float t[32][33];
  const int ct = blockIdx.x, kt = blockIdx.y;
  const int j = threadIdx.x & 31, ig = threadIdx.x >> 5;
#pragma unroll
  for (int ii = 0; ii < 4; ++ii) {
    int i = ig * 4 + ii;
    t[i][j] = src[(size_t)(kt * 32 + i) * WLD + ct * 32 + j];
  }
  __syncthreads();
#pragma unroll
  for (int ii = 0; ii < 4; ++ii) {
    int cc = ig * 4 + ii;
    dst[(size_t)(ct * 32 + cc) * 1024 + kt * 32 + j] = (__bf16)t[j][cc];
  }
}

// ---------------- MFMA GEMM (A row-major bf16 t-major rows, B^T bf16 [n][k]) ----------------
template <int MODE>
__global__ __launch_bounds__(256) void gemm_bt(const __bf16* __restrict__ A, int lda,
                                               const __bf16* __restrict__ BT,
                                               const float* __restrict__ bias,
                                               __bf16* __restrict__ gbuf,
                                               const float* __restrict__ xf,
                                               float* __restrict__ hout, int ncols) {
  __shared__ __bf16 As[128][48];
  __shared__ __bf16 Bs[128][48];
  const int tid = threadIdx.x;
  const int lane = tid & 63, wave = tid >> 6;
  const int tm = blockIdx.y, tn = blockIdx.x;
  const int wm = (wave & 1) * 64, wn = (wave >> 1) * 64;
  floatx4 acc[4][4] = {};
  const int c = tid & 3, r0 = tid >> 2;
  const size_t arow = (size_t)tm * 128;
  const size_t brow = (size_t)tn * 128;

  for (int kk = 0; kk < 1024; kk += 32) {
    *reinterpret_cast<uint4*>(&As[r0][c * 8]) =
        *reinterpret_cast<const uint4*>(A + (arow + r0) * (size_t)lda + kk + c * 8);
    *reinterpret_cast<uint4*>(&As[r0 + 64][c * 8]) =
        *reinterpret_cast<const uint4*>(A + (arow + r0 + 64) * (size_t)lda + kk + c * 8);
    *reinterpret_cast<uint4*>(&Bs[r0][c * 8]) =
        *reinterpret_cast<const uint4*>(BT + (brow + r0) * 1024 + kk + c * 8);
    *reinterpret_cast<uint4*>(&Bs[r0 + 64][c * 8]) =
        *reinterpret_cast<const uint4*>(BT + (brow + r0 + 64) * 1024 + kk + c * 8);
    __syncthreads();
    const int mr = lane & 15, kg = (lane >> 4) * 8;
    bf16x8 af[4], bfr[4];
#pragma unroll
    for (int f = 0; f < 4; ++f) af[f] = *reinterpret_cast<const bf16x8*>(&As[wm + f * 16 + mr][kg]);
#pragma unroll
    for (int f = 0; f < 4; ++f) bfr[f] = *reinterpret_cast<const bf16x8*>(&Bs[wn + f * 16 + mr][kg]);
#pragma unroll
    for (int fi = 0; fi < 4; ++fi)
#pragma unroll
      for (int fj = 0; fj < 4; ++fj)
        acc[fi][fj] = __builtin_amdgcn_mfma_f32_16x16x32_bf16(af[fi], bfr[fj], acc[fi][fj], 0, 0, 0);
    __syncthreads();
  }

#pragma unroll
  for (int fi = 0; fi < 4; ++fi)
#pragma unroll
    for (int fj = 0; fj < 4; ++fj) {
      const int row0 = tm * 128 + wm + fi * 16 + (lane >> 4) * 4;
      const int col = tn * 128 + wn + fj * 16 + (lane & 15);
#pragma unroll
      for (int r = 0; r < 4; ++r) {
        const size_t row = (size_t)(row0 + r);
        float v = acc[fi][fj][r];
        if (MODE == 0 || MODE == 1) {
          gbuf[row * 3072 + col] = (__bf16)(v + bias[col]);
        } else if (MODE == 2) {
          float g = sigmoidf_(v + (float)gbuf[row * 3072 + col]);
          const size_t xrow = (size_t)(row & 31) * 512 + (row >> 5);
          if (col < 1024)
            gbuf[row * 3072 + col] = (__bf16)g;                                   // ud
          else
            gbuf[row * 3072 + col] = (__bf16)(g * xf[xrow * 1024 + (col - 1024)]); // rd*x
        } else {
          float hcd = tanhf_(v + (float)gbuf[row * 3072 + 2048 + col]);
          float ud = (float)gbuf[row * 3072 + col];
          const size_t xrow = (size_t)(row & 31) * 512 + (row >> 5);
          float xv = xf[xrow * 1024 + col];
          hout[xrow * 1024 + col] = xv + ud * (hcd - xv);
        }
      }
    }
}

// ---------------- persistent recurrence (barrier-free tagged dataflow) ----------------
// 64 WGs x 512 threads. WG b owns gg cols {16b..} u {1024+16b..} and hc cols {16b..}.
// Broadcast vectors (ht, r*ht) travel as self-validating tagged 8B words at LIC:
//   word = (epoch<<32) | 2 bf16.  Consumers poll the data itself — no barrier, no
//   RMW counter, no producer ack, no flag->data round trip. Wave w only waits on
//   its 8 K-range producers. Epochs: ht@step t = t+1 (init publish tag 1, end of
//   step t publishes t+2), rh@step t = t+1. Overwrite of epoch e happens only after
//   every WG consumed e (consumption is a data dependency of the next publish).
#define SMEM_BYTES 136960
#define WS 1032
__global__ __launch_bounds__(512) void recur_kernel(
    const __bf16* __restrict__ gates, const float* __restrict__ state,
    const __bf16* __restrict__ whtg_t, const __bf16* __restrict__ whtc_t,
    u64* __restrict__ ht_w, u64* __restrict__ rh_w,
    __bf16* __restrict__ htseq, float* __restrict__ otail) {
  extern __shared__ char smem[];
  __bf16* Wg  = (__bf16*)smem;                   // [32][WS]  66048 B
  __bf16* Wc  = (__bf16*)(smem + 66048);         // [16][WS]  33024 B
  float*  red = (float*)(smem + 99072);          // [8][32][33] 33792 B
  float*  u_s = (float*)(smem + 132864);         // [32][16]   2048 B
  float*  hp_s= (float*)(smem + 134912);         // [32][16]   2048 B (fp32 ht master, own cols)

  const int b = blockIdx.x, tid = threadIdx.x;
  const int lane = tid & 63, w = tid >> 6;       // 8 waves; wave w owns K range [w*128, w*128+128)
  const int mr = lane & 15, kq = lane >> 4;
  const int k0 = w * 128;
  const int wbase = (k0 >> 1) + kq * 4;          // u64-word offset within a row

  // ---- init: weights -> LDS ----
  for (int idx = tid; idx < 4096; idx += 512) {
    int row = idx >> 7, seg = idx & 127;
    int src = (row < 16) ? (b * 16 + row) : (1024 + b * 16 + row - 16);
    *reinterpret_cast<uint4*>(Wg + row * WS + seg * 8) =
        *reinterpret_cast<const uint4*>(whtg_t + (size_t)src * 1024 + seg * 8);
  }
  for (int idx = tid; idx < 2048; idx += 512) {
    int row = idx >> 7, seg = idx & 127;
    *reinterpret_cast<uint4*>(Wc + row * WS + seg * 8) =
        *reinterpret_cast<const uint4*>(whtc_t + (size_t)(b * 16 + row) * 1024 + seg * 8);
  }
  // ---- init: state -> hp_s, direct tagged publish of ht epoch 1 ----
  {
    int n = tid >> 4, cc = tid & 15;
    float sv = state[n * 1024 + b * 16 + cc];
    hp_s[n * 16 + cc] = sv;
    float so = __shfl_xor(sv, 1);
    if (!(cc & 1))
      ast64(ht_w + (size_t)n * 512 + b * 8 + (cc >> 1), mk_tag(1u, sv, so));
  }
  __syncthreads();

  for (int t = 0; t < 512; ++t) {
    const uint e = (uint)t + 1u;
    // ================= phase A: gg = sigmoid(gates + ht @ Whtg) =================
    {
      // prefetch gates (HBM latency hides under the poll)
      __bf16 graw0, graw1;
      {
        int n = tid >> 5, col = tid & 31;
        int cc = (col < 16) ? (b * 16 + col) : (1024 + b * 16 + col - 16);
        graw0 = gates[(size_t)(t * 32 + n) * 3072 + cc];
        int o2 = tid + 512, n2 = o2 >> 5, col2 = o2 & 31;
        int cc2 = (col2 < 16) ? (b * 16 + col2) : (1024 + b * 16 + col2 - 16);
        graw1 = gates[(size_t)(t * 32 + n2) * 3072 + cc2];
      }
      // cheap poll: 1 representative word per producer of this wave's K range
      {
        bool rdy;
        do {
          u64 sgl = ald64(ht_w + (size_t)((w << 3) + (lane & 7)) * 8);
          rdy = ((uint)(sgl >> 32) == e);
        } while (!__all(rdy));
      }
      // full load + validate (re-issue on stragglers; typically passes first try)
      u64 wa[4][4], wb[4][4];
      bool ok;
      do {
        ok = true;
#pragma unroll
        for (int c2 = 0; c2 < 4; ++c2) {
          const size_t o0 = (size_t)mr * 512 + wbase + c2 * 16;
          const size_t o1 = o0 + 16 * 512;
#pragma unroll
          for (int j = 0; j < 4; ++j) {
            wa[c2][j] = ald64(ht_w + o0 + j);
            wb[c2][j] = ald64(ht_w + o1 + j);
          }
        }
#pragma unroll
        for (int c2 = 0; c2 < 4; ++c2)
#pragma unroll
          for (int j = 0; j < 4; ++j)
            ok = ok && ((uint)(wa[c2][j] >> 32) == e) && ((uint)(wb[c2][j] >> 32) == e);
      } while (!__all(ok));

      floatx4 acc[2][2] = {};
#pragma unroll
      for (int c2 = 0; c2 < 4; ++c2) {
        union { uint4 u; bf16x8 v; } fa, fb;
        fa.u = make_uint4((uint)wa[c2][0], (uint)wa[c2][1], (uint)wa[c2][2], (uint)wa[c2][3]);
        fb.u = make_uint4((uint)wb[c2][0], (uint)wb[c2][1], (uint)wb[c2][2], (uint)wb[c2][3]);
        const int kb = k0 + c2 * 32 + kq * 8;
        bf16x8 b0 = *reinterpret_cast<const bf16x8*>(Wg + mr * WS + kb);
        bf16x8 b1 = *reinterpret_cast<const bf16x8*>(Wg + (16 + mr) * WS + kb);
        acc[0][0] = __builtin_amdgcn_mfma_f32_16x16x32_bf16(fa.v, b0, acc[0][0], 0, 0, 0);
        acc[0][1] = __builtin_amdgcn_mfma_f32_16x16x32_bf16(fa.v, b1, acc[0][1], 0, 0, 0);
        acc[1][0] = __builtin_amdgcn_mfma_f32_16x16x32_bf16(fb.v, b0, acc[1][0], 0, 0, 0);
        acc[1][1] = __builtin_amdgcn_mfma_f32_16x16x32_bf16(fb.v, b1, acc[1][1], 0, 0, 0);
      }
#pragma unroll
      for (int ai = 0; ai < 2; ++ai)
#pragma unroll
        for (int cj = 0; cj < 2; ++cj)
#pragma unroll
          for (int r = 0; r < 4; ++r)
            red[w * 1056 + (ai * 16 + kq * 4 + r) * 33 + cj * 16 + mr] = acc[ai][cj][r];
      __syncthreads();
      // reduce over 8 waves; epilogue publishes r*ht directly (all waves, tagged)
      {
        int n = tid >> 5, col = tid & 31;
        float s = 0.f;
#pragma unroll
        for (int w8 = 0; w8 < 8; ++w8) s += red[w8 * 1056 + n * 33 + col];
        float gg = sigmoidf_(s + (float)graw0);
        float pub = 0.f;
        if (col < 16) u_s[n * 16 + col] = gg;
        else pub = gg * hp_s[n * 16 + (col - 16)];
        float po = __shfl_xor(pub, 1);
        if (col >= 16 && !(col & 1))
          ast64(rh_w + (size_t)n * 512 + b * 8 + ((col - 16) >> 1), mk_tag(e, pub, po));
        int o2 = tid + 512, n2 = o2 >> 5, col2 = o2 & 31;
        float s2 = 0.f;
#pragma unroll
        for (int w8 = 0; w8 < 8; ++w8) s2 += red[w8 * 1056 + n2 * 33 + col2];
        float gg2 = sigmoidf_(s2 + (float)graw1);
        float pub2 = 0.f;
        if (col2 < 16) u_s[n2 * 16 + col2] = gg2;
        else pub2 = gg2 * hp_s[n2 * 16 + (col2 - 16)];
        float po2 = __shfl_xor(pub2, 1);
        if (col2 >= 16 && !(col2 & 1))
          ast64(rh_w + (size_t)n2 * 512 + b * 8 + ((col2 - 16) >> 1), mk_tag(e, pub2, po2));
      }
      __syncthreads();
    }
    // ================= phase B: hc = tanh(gates_c + (r*ht) @ Whtc); update =================
    {
      __bf16 gcraw;
      {
        int n = tid >> 4, col = tid & 15;
        gcraw = gates[(size_t)(t * 32 + n) * 3072 + 2048 + b * 16 + col];
      }
      {
        bool rdy;
        do {
          u64 sgl = ald64(rh_w + (size_t)((w << 3) + (lane & 7)) * 8);
          rdy = ((uint)(sgl >> 32) == e);
        } while (!__all(rdy));
      }
      u64 wa[4][4], wb[4][4];
      bool ok;
      do {
        ok = true;
#pragma unroll
        for (int c2 = 0; c2 < 4; ++c2) {
          const size_t o0 = (size_t)mr * 512 + wbase + c2 * 16;
          const size_t o1 = o0 + 16 * 512;
#pragma unroll
          for (int j = 0; j < 4; ++j) {
            wa[c2][j] = ald64(rh_w + o0 + j);
            wb[c2][j] = ald64(rh_w + o1 + j);
          }
        }
#pragma unroll
        for (int c2 = 0; c2 < 4; ++c2)
#pragma unroll
          for (int j = 0; j < 4; ++j)
            ok = ok && ((uint)(wa[c2][j] >> 32) == e) && ((uint)(wb[c2][j] >> 32) == e);
      } while (!__all(ok));

      floatx4 acc[2] = {};
#pragma unroll
      for (int c2 = 0; c2 < 4; ++c2) {
        union { uint4 u; bf16x8 v; } fa, fb;
        fa.u = make_uint4((uint)wa[c2][0], (uint)wa[c2][1], (uint)wa[c2][2], (uint)wa[c2][3]);
        fb.u = make_uint4((uint)wb[c2][0], (uint)wb[c2][1], (uint)wb[c2][2], (uint)wb[c2][3]);
        const int kb = k0 + c2 * 32 + kq * 8;
        bf16x8 bb = *reinterpret_cast<const bf16x8*>(Wc + mr * WS + kb);
        acc[0] = __builtin_amdgcn_mfma_f32_16x16x32_bf16(fa.v, bb, acc[0], 0, 0, 0);
        acc[1] = __builtin_amdgcn_mfma_f32_16x16x32_bf16(fb.v, bb, acc[1], 0, 0, 0);
      }
#pragma unroll
      for (int ai = 0; ai < 2; ++ai)
#pragma unroll
        for (int r = 0; r < 4; ++r)
          red[w * 1056 + (ai * 16 + kq * 4 + r) * 33 + mr] = acc[ai][r];
      __syncthreads();
      {
        int n = tid >> 4, col = tid & 15;
        float s = 0.f;
#pragma unroll
        for (int w8 = 0; w8 < 8; ++w8) s += red[w8 * 1056 + n * 33 + col];
        float hc = tanhf_(s + (float)gcraw);
        float hp = hp_s[n * 16 + col];
        float uu = u_s[n * 16 + col];
        float hn = hp + uu * (hc - hp);
        hp_s[n * 16 + col] = hn;
        htseq[(size_t)(t * 32 + n) * 1024 + b * 16 + col] = (__bf16)hn;
        if (t == 511) otail[n * 1024 + b * 16 + col] = hn;
        float ho = __shfl_xor(hn, 1);
        if (!(col & 1))
          ast64(ht_w + (size_t)n * 512 + b * 8 + (col >> 1), mk_tag(e + 1u, hn, ho));
      }
      __syncthreads();
    }
  }
}

// ---------------- launch ----------------

extern "C" void kernel_launch(void* const* d_in, const int* in_sizes, int n_in,
                              void* d_out, int out_size, void* d_ws, size_t ws_size,
                              hipStream_t stream) {
  const float* x = (const float*)d_in[0];
  const float* state = (const float*)d_in[1];
  const float* weight = (const float*)d_in[2];
  const float* bias = (const float*)d_in[3];
  float* out = (float*)d_out;
  char* ws = (char*)d_ws;

  __bf16* gates  = (__bf16*)(ws + OFF_GATES);
  __bf16* xb     = (__bf16*)(ws + OFF_XB);
  __bf16* htseq  = (__bf16*)(ws + OFF_HTSEQ);
  __bf16* whtg_t = (__bf16*)(ws + OFF_WHTGT);
  __bf16* whtc_t = (__bf16*)(ws + OFF_WHTCT);
  __bf16* wxtt   = (__bf16*)(ws + OFF_WXTT);
  __bf16* whdt   = (__bf16*)(ws + OFF_WHDT);
  __bf16* wxd1t  = (__bf16*)(ws + OFF_WXD1T);
  __bf16* wxd2t  = (__bf16*)(ws + OFF_WXD2T);
  u64*    tags   = (u64*)(ws + OFF_TAGS);
  u64*    ht_w   = tags;
  u64*    rh_w   = tags + 16384;

  // prep: x -> bf16 t-major, weight blocks -> bf16 B^T
  hipLaunchKernelGGL(convert_x, dim3(16384), dim3(256), 0, stream, (const float4*)x, xb);
  hipLaunchKernelGGL(transpose_conv, dim3(96, 32), dim3(256), 0, stream, weight, wxtt);
  hipLaunchKernelGGL(transpose_conv, dim3(64, 32), dim3(256), 0, stream, weight + 3072, wxd1t);
  hipLaunchKernelGGL(transpose_conv, dim3(32, 32), dim3(256), 0, stream, weight + 5120, wxd2t);
  hipLaunchKernelGGL(transpose_conv, dim3(96, 32), dim3(256), 0, stream,
                     weight + (size_t)1024 * WLD + 3072, whdt);
  hipLaunchKernelGGL(transpose_conv, dim3(64, 32), dim3(256), 0, stream,
                     weight + (size_t)1024 * WLD, whtg_t);
  hipLaunchKernelGGL(transpose_conv, dim3(32, 32), dim3(256), 0, stream,
                     weight + (size_t)1024 * WLD + 2048, whtc_t);

  // gates = x @ Wxt + bias[:3H]   (t-major rows)
  hipLaunchKernelGGL((gemm_bt<0>), dim3(24, 128), dim3(256), 0, stream,
                     xb, 1024, wxtt, bias, gates, (const float*)nullptr, (float*)nullptr, 3072);

  // zero tagged buffers (overlay wxtt — must follow gemm<0>, precede recur)
  hipLaunchKernelGGL(zero_tags, dim3(128), dim3(256), 0, stream, tags);

  // recurrence (cooperative, 64 WGs x 512 threads, barrier-free tagged dataflow)
  {
    (void)hipFuncSetAttribute(reinterpret_cast<const void*>(recur_kernel),
                              hipFuncAttributeMaxDynamicSharedMemorySize, SMEM_BYTES);
    const __bf16* gatesc = gates;
    float* otail = out + 16777216;
    void* args[8];
    args[0] = (void*)&gatesc; args[1] = (void*)&state;  args[2] = (void*)&whtg_t;
    args[3] = (void*)&whtc_t; args[4] = (void*)&ht_w;   args[5] = (void*)&rh_w;
    args[6] = (void*)&htseq;  args[7] = (void*)&otail;
    hipLaunchCooperativeKernel(recur_kernel, dim3(64), dim3(512), args, SMEM_BYTES, stream);
  }

  // gd = ht_seq @ Whd + bias[3H:]  (into gates buffer)
  hipLaunchKernelGGL((gemm_bt<1>), dim3(24, 128), dim3(256), 0, stream,
                     htseq, 1024, whdt, bias + 3072, gates, (const float*)nullptr,
                     (float*)nullptr, 3072);
  // g2 = sigmoid(gd[:, :2D] + x @ Wxd[:, :2D]); ud/rx in-place
  hipLaunchKernelGGL((gemm_bt<2>), dim3(16, 128), dim3(256), 0, stream,
                     xb, 1024, wxd1t, bias, gates, x, (float*)nullptr, 2048);
  // hcd = tanh(gd[:, 2D:] + rx @ Wxd[:, 2D:]); h = x + ud*(hcd - x)
  hipLaunchKernelGGL((gemm_bt<3>), dim3(8, 128), dim3(256), 0, stream,
                     gates + 1024, 3072, wxd2t, bias, gates, x, out, 1024);
}

// Round 3
// 6238.673 us; speedup vs baseline: 1.5422x; 1.5422x over previous
//
#include <hip/hip_runtime.h>
#include <cstdint>
#include <cstddef>

typedef unsigned int uint;
typedef unsigned short ushort;
typedef unsigned long long u64;
typedef __attribute__((ext_vector_type(8))) __bf16 bf16x8;
typedef __attribute__((ext_vector_type(4))) __bf16 bf16x4v;
typedef __attribute__((ext_vector_type(4))) float floatx4;

#define WLD 6144      // weight row stride = 3*(D+H)

// ---- workspace layout (bytes). Row convention for xb/gates/htseq: r = t*32 + n (t-major).
static const size_t OFF_GATES = 0;              // bf16 16384x3072
static const size_t OFF_XB    = 100663296;      // bf16 16384x1024
static const size_t OFF_HTSEQ = 134217728;      // bf16 16384x1024
// whtg_t/whtc_t overlay the htseq region: consumed (into LDS) before any htseq write.
static const size_t OFF_WHTGT = OFF_HTSEQ;              // bf16 2048x1024
static const size_t OFF_WHTCT = OFF_HTSEQ + 4194304;    // bf16 1024x1024
static const size_t OFF_WXTT  = 167772160;      // bf16 3072x1024 (B^T)
// Comm region overlays wxtt (dead after gemm<0>, which precedes zero_flags + recur):
//   ht data : u64[2][8192]  (parity-double-buffered 32x1024 bf16, 4 bf16/u64, 256 u64/row)
//   rh data : u64[2][8192]
//   fht     : u64[64*16]    (per-producer flags, 128B apart)
//   frh     : u64[64*16]
static const size_t OFF_COMM  = OFF_WXTT;
static const size_t OFF_WHDT  = 174063616;      // bf16 3072x1024
static const size_t OFF_WXD1T = 180355072;      // bf16 2048x1024
static const size_t OFF_WXD2T = 184549376;      // bf16 1024x1024

__device__ __forceinline__ float sigmoidf_(float x) { return 1.f / (1.f + __expf(-x)); }
__device__ __forceinline__ float tanhf_(float x) { float e = __expf(2.f * x); return 1.f - 2.f / (e + 1.f); }

// agent-scope relaxed atomics: operate at LIC (device coherence point).
__device__ __forceinline__ u64 ald64(const u64* p) {
  return __hip_atomic_load(p, __ATOMIC_RELAXED, __HIP_MEMORY_SCOPE_AGENT);
}
__device__ __forceinline__ void ast64(u64* p, u64 v) {
  __hip_atomic_store(p, v, __ATOMIC_RELAXED, __HIP_MEMORY_SCOPE_AGENT);
}
__device__ __forceinline__ ushort bfb(float v) {
  union { __bf16 b; ushort u; } t; t.b = (__bf16)v; return t.u;
}
// pack 4 bf16 (cols c..c+3, this lane holds col c with c&3==0) into one u64
__device__ __forceinline__ u64 pack4(float v) {
  ushort h = bfb(v);
  uint p2 = (uint)h | ((uint)(ushort)__shfl_xor((int)h, 1) << 16);
  u64 p4 = (u64)p2 | ((u64)(uint)__shfl_xor((int)p2, 2) << 32);
  return p4;
}

// ---------------- prep kernels ----------------

// x [n][t][1024] fp32 -> xb bf16 rows r=t*32+n.
__global__ __launch_bounds__(256) void convert_x(const float4* __restrict__ x4,
                                                 __bf16* __restrict__ xb) {
  const int s = blockIdx.x;              // source row n*512+t
  const int n = s >> 9, t = s & 511;
  const int d = (t << 5) | n;            // dest row t*32+n
  float4 v = x4[(size_t)s * 256 + threadIdx.x];
  bf16x4v o = { (__bf16)v.x, (__bf16)v.y, (__bf16)v.z, (__bf16)v.w };
  *reinterpret_cast<bf16x4v*>(xb + (size_t)d * 1024 + threadIdx.x * 4) = o;
}

// zero the flag region (2048 u64) at the coherence point.
__global__ __launch_bounds__(256) void zero_flags(u64* __restrict__ f) {
  ast64(f + (size_t)blockIdx.x * 256 + threadIdx.x, 0ull);
}

// src: fp32 block, row stride WLD, 1024 rows (k), gridDim.x*32 cols. dst: bf16 [c][k].
__global__ __launch_bounds__(256) void transpose_conv(const float* __restrict__ src,
                                                      __bf16* __restrict__ dst) {
  __shared__ float t[32][33];
  const int ct = blockIdx.x, kt = blockIdx.y;
  const int j = threadIdx.x & 31, ig = threadIdx.x >> 5;
#pragma unroll
  for (int ii = 0; ii < 4; ++ii) {
    int i = ig * 4 + ii;
    t[i][j] = src[(size_t)(kt * 32 + i) * WLD + ct * 32 + j];
  }
  __syncthreads();
#pragma unroll
  for (int ii = 0; ii < 4; ++ii) {
    int cc = ig * 4 + ii;
    dst[(size_t)(ct * 32 + cc) * 1024 + kt * 32 + j] = (__bf16)t[j][cc];
  }
}

// ---------------- MFMA GEMM (A row-major bf16 t-major rows, B^T bf16 [n][k]) ----------------
template <int MODE>
__global__ __launch_bounds__(256) void gemm_bt(const __bf16* __restrict__ A, int lda,
                                               const __bf16* __restrict__ BT,
                                               const float* __restrict__ bias,
                                               __bf16* __restrict__ gbuf,
                                               const float* __restrict__ xf,
                                               float* __restrict__ hout, int ncols) {
  __shared__ __bf16 As[128][48];
  __shared__ __bf16 Bs[128][48];
  const int tid = threadIdx.x;
  const int lane = tid & 63, wave = tid >> 6;
  const int tm = blockIdx.y, tn = blockIdx.x;
  const int wm = (wave & 1) * 64, wn = (wave >> 1) * 64;
  floatx4 acc[4][4] = {};
  const int c = tid & 3, r0 = tid >> 2;
  const size_t arow = (size_t)tm * 128;
  const size_t brow = (size_t)tn * 128;

  for (int kk = 0; kk < 1024; kk += 32) {
    *reinterpret_cast<uint4*>(&As[r0][c * 8]) =
        *reinterpret_cast<const uint4*>(A + (arow + r0) * (size_t)lda + kk + c * 8);
    *reinterpret_cast<uint4*>(&As[r0 + 64][c * 8]) =
        *reinterpret_cast<const uint4*>(A + (arow + r0 + 64) * (size_t)lda + kk + c * 8);
    *reinterpret_cast<uint4*>(&Bs[r0][c * 8]) =
        *reinterpret_cast<const uint4*>(BT + (brow + r0) * 1024 + kk + c * 8);
    *reinterpret_cast<uint4*>(&Bs[r0 + 64][c * 8]) =
        *reinterpret_cast<const uint4*>(BT + (brow + r0 + 64) * 1024 + kk + c * 8);
    __syncthreads();
    const int mr = lane & 15, kg = (lane >> 4) * 8;
    bf16x8 af[4], bfr[4];
#pragma unroll
    for (int f = 0; f < 4; ++f) af[f] = *reinterpret_cast<const bf16x8*>(&As[wm + f * 16 + mr][kg]);
#pragma unroll
    for (int f = 0; f < 4; ++f) bfr[f] = *reinterpret_cast<const bf16x8*>(&Bs[wn + f * 16 + mr][kg]);
#pragma unroll
    for (int fi = 0; fi < 4; ++fi)
#pragma unroll
      for (int fj = 0; fj < 4; ++fj)
        acc[fi][fj] = __builtin_amdgcn_mfma_f32_16x16x32_bf16(af[fi], bfr[fj], acc[fi][fj], 0, 0, 0);
    __syncthreads();
  }

#pragma unroll
  for (int fi = 0; fi < 4; ++fi)
#pragma unroll
    for (int fj = 0; fj < 4; ++fj) {
      const int row0 = tm * 128 + wm + fi * 16 + (lane >> 4) * 4;
      const int col = tn * 128 + wn + fj * 16 + (lane & 15);
#pragma unroll
      for (int r = 0; r < 4; ++r) {
        const size_t row = (size_t)(row0 + r);
        float v = acc[fi][fj][r];
        if (MODE == 0 || MODE == 1) {
          gbuf[row * 3072 + col] = (__bf16)(v + bias[col]);
        } else if (MODE == 2) {
          float g = sigmoidf_(v + (float)gbuf[row * 3072 + col]);
          const size_t xrow = (size_t)(row & 31) * 512 + (row >> 5);
          if (col < 1024)
            gbuf[row * 3072 + col] = (__bf16)g;                                   // ud
          else
            gbuf[row * 3072 + col] = (__bf16)(g * xf[xrow * 1024 + (col - 1024)]); // rd*x
        } else {
          float hcd = tanhf_(v + (float)gbuf[row * 3072 + 2048 + col]);
          float ud = (float)gbuf[row * 3072 + col];
          const size_t xrow = (size_t)(row & 31) * 512 + (row >> 5);
          float xv = xf[xrow * 1024 + col];
          hout[xrow * 1024 + col] = xv + ud * (hcd - xv);
        }
      }
    }
}

// ---------------- persistent recurrence (flag-gated dataflow, untagged data) ----------------
// 64 WGs x 512 threads. WG b owns gg cols {16b..} u {1024+16b..} and hc cols {16b..}.
// Broadcast vectors (ht, r*ht) live in parity-double-buffered LIC arrays
// (4 bf16 / u64, row stride 256 u64 = 1024 bf16 cols).
// Producer: data stores -> __syncthreads (drains vmcnt => data at LIC) -> ONE flag store.
// Consumer wave w: 8 lanes poll the 8 producer flags covering its K range (reads
// pipeline at LIC — no RMW serialization), then loads data ONCE (guaranteed valid).
// Parity reuse is safe: every phase consumes from ALL 64 producers, so writing
// epoch e+2 transitively requires every WG to have finished reading epoch e.
#define SMEM_BYTES 136960
#define WS 1032
__global__ __launch_bounds__(512) void recur_kernel(
    const __bf16* __restrict__ gates, const float* __restrict__ state,
    const __bf16* __restrict__ whtg_t, const __bf16* __restrict__ whtc_t,
    u64* __restrict__ ht_w, u64* __restrict__ rh_w,
    u64* __restrict__ fht, u64* __restrict__ frh,
    __bf16* __restrict__ htseq, float* __restrict__ otail) {
  extern __shared__ char smem[];
  __bf16* Wg  = (__bf16*)smem;                   // [32][WS]  66048 B
  __bf16* Wc  = (__bf16*)(smem + 66048);         // [16][WS]  33024 B
  float*  red = (float*)(smem + 99072);          // [8][32][33] 33792 B
  float*  u_s = (float*)(smem + 132864);         // [32][16]   2048 B
  float*  hp_s= (float*)(smem + 134912);         // [32][16]   2048 B (fp32 ht master, own cols)

  const int b = blockIdx.x, tid = threadIdx.x;
  const int lane = tid & 63, w = tid >> 6;       // 8 waves; wave w owns K range [w*128, w*128+128)
  const int mr = lane & 15, kq = lane >> 4;
  // u64 base indices into a 32x1024 bf16 buffer (256 u64 per row)
  const int base0 = mr * 256 + w * 32 + kq * 2;         // + c2*8
  const int base1 = (16 + mr) * 256 + w * 32 + kq * 2;  // + c2*8

  // ---- init: weights -> LDS ----
  for (int idx = tid; idx < 4096; idx += 512) {
    int row = idx >> 7, seg = idx & 127;
    int src = (row < 16) ? (b * 16 + row) : (1024 + b * 16 + row - 16);
    *reinterpret_cast<uint4*>(Wg + row * WS + seg * 8) =
        *reinterpret_cast<const uint4*>(whtg_t + (size_t)src * 1024 + seg * 8);
  }
  for (int idx = tid; idx < 2048; idx += 512) {
    int row = idx >> 7, seg = idx & 127;
    *reinterpret_cast<uint4*>(Wc + row * WS + seg * 8) =
        *reinterpret_cast<const uint4*>(whtc_t + (size_t)(b * 16 + row) * 1024 + seg * 8);
  }
  // ---- init: state -> hp_s, publish ht@1 (parity 1) ----
  {
    int n = tid >> 4, cc = tid & 15;
    float sv = state[n * 1024 + b * 16 + cc];
    hp_s[n * 16 + cc] = sv;
    u64 p4 = pack4(sv);
    if (!(cc & 3)) ast64(ht_w + 8192 + n * 256 + b * 4 + (cc >> 2), p4);
  }
  __syncthreads();                                // drains vmcnt: data at LIC
  if (tid == 0) {
    asm volatile("s_waitcnt vmcnt(0)" ::: "memory");
    ast64(fht + b * 16, 1ull);
  }

  for (int t = 0; t < 512; ++t) {
    const uint e = (uint)t + 1u;
    const u64* htb = ht_w + (size_t)(e & 1) * 8192;
    u64*       rhb = rh_w + (size_t)(e & 1) * 8192;
    float hn_keep = 0.f;
    // ================= phase A: gg = sigmoid(gates + ht @ Whtg) =================
    {
      // prefetch gates (HBM/L2 latency hides under the flag poll)
      __bf16 graw0, graw1;
      {
        int n = tid >> 5, col = tid & 31;
        int cc = (col < 16) ? (b * 16 + col) : (1024 + b * 16 + col - 16);
        graw0 = gates[(size_t)(t * 32 + n) * 3072 + cc];
        int o2 = tid + 512, n2 = o2 >> 5;
        graw1 = gates[(size_t)(t * 32 + n2) * 3072 + cc];
      }
      // wait for the 8 producers of this wave's K range
      {
        const u64* fp = fht + (size_t)(w * 8 + (lane & 7)) * 16;
        bool rdy;
        do {
          u64 v = (lane < 8) ? ald64(fp) : (u64)e;
          rdy = (v >= (u64)e);
        } while (!__all(rdy));
        asm volatile("" ::: "memory");
      }
      // single-shot data load (guaranteed valid)
      u64 wa[4][2], wb[4][2];
#pragma unroll
      for (int c2 = 0; c2 < 4; ++c2) {
        wa[c2][0] = ald64(htb + base0 + c2 * 8);
        wa[c2][1] = ald64(htb + base0 + c2 * 8 + 1);
        wb[c2][0] = ald64(htb + base1 + c2 * 8);
        wb[c2][1] = ald64(htb + base1 + c2 * 8 + 1);
      }
      floatx4 acc[2][2] = {};
#pragma unroll
      for (int c2 = 0; c2 < 4; ++c2) {
        union { uint4 u; bf16x8 v; } fa, fb;
        fa.u = make_uint4((uint)wa[c2][0], (uint)(wa[c2][0] >> 32),
                          (uint)wa[c2][1], (uint)(wa[c2][1] >> 32));
        fb.u = make_uint4((uint)wb[c2][0], (uint)(wb[c2][0] >> 32),
                          (uint)wb[c2][1], (uint)(wb[c2][1] >> 32));
        const int kb = w * 128 + c2 * 32 + kq * 8;
        bf16x8 b0 = *reinterpret_cast<const bf16x8*>(Wg + mr * WS + kb);
        bf16x8 b1 = *reinterpret_cast<const bf16x8*>(Wg + (16 + mr) * WS + kb);
        acc[0][0] = __builtin_amdgcn_mfma_f32_16x16x32_bf16(fa.v, b0, acc[0][0], 0, 0, 0);
        acc[0][1] = __builtin_amdgcn_mfma_f32_16x16x32_bf16(fa.v, b1, acc[0][1], 0, 0, 0);
        acc[1][0] = __builtin_amdgcn_mfma_f32_16x16x32_bf16(fb.v, b0, acc[1][0], 0, 0, 0);
        acc[1][1] = __builtin_amdgcn_mfma_f32_16x16x32_bf16(fb.v, b1, acc[1][1], 0, 0, 0);
      }
#pragma unroll
      for (int ai = 0; ai < 2; ++ai)
#pragma unroll
        for (int cj = 0; cj < 2; ++cj)
#pragma unroll
          for (int r = 0; r < 4; ++r)
            red[w * 1056 + (ai * 16 + kq * 4 + r) * 33 + cj * 16 + mr] = acc[ai][cj][r];
      __syncthreads();
      // reduce over 8 waves; epilogue publishes r*ht data
      {
        int n = tid >> 5, col = tid & 31;
        float s = 0.f;
#pragma unroll
        for (int w8 = 0; w8 < 8; ++w8) s += red[w8 * 1056 + n * 33 + col];
        float gg = sigmoidf_(s + (float)graw0);
        float pub = (col >= 16) ? gg * hp_s[n * 16 + (col - 16)] : 0.f;
        if (col < 16) u_s[n * 16 + col] = gg;
        u64 p4 = pack4(pub);
        if (col >= 16 && !(col & 3))
          ast64(rhb + n * 256 + b * 4 + ((col - 16) >> 2), p4);
        int o2 = tid + 512, n2 = o2 >> 5;
        float s2 = 0.f;
#pragma unroll
        for (int w8 = 0; w8 < 8; ++w8) s2 += red[w8 * 1056 + n2 * 33 + col];
        float gg2 = sigmoidf_(s2 + (float)graw1);
        float pub2 = (col >= 16) ? gg2 * hp_s[n2 * 16 + (col - 16)] : 0.f;
        if (col < 16) u_s[n2 * 16 + col] = gg2;
        u64 p42 = pack4(pub2);
        if (col >= 16 && !(col & 3))
          ast64(rhb + n2 * 256 + b * 4 + ((col - 16) >> 2), p42);
      }
      __syncthreads();                            // drains vmcnt: rh data at LIC
      if (tid == 0) {
        asm volatile("s_waitcnt vmcnt(0)" ::: "memory");
        ast64(frh + b * 16, (u64)e);
      }
    }
    // ================= phase B: hc = tanh(gates_c + (r*ht) @ Whtc); update =================
    {
      __bf16 gcraw;
      {
        int n = tid >> 4, col = tid & 15;
        gcraw = gates[(size_t)(t * 32 + n) * 3072 + 2048 + b * 16 + col];
      }
      {
        const u64* fp = frh + (size_t)(w * 8 + (lane & 7)) * 16;
        bool rdy;
        do {
          u64 v = (lane < 8) ? ald64(fp) : (u64)e;
          rdy = (v >= (u64)e);
        } while (!__all(rdy));
        asm volatile("" ::: "memory");
      }
      u64 wa[4][2], wb[4][2];
#pragma unroll
      for (int c2 = 0; c2 < 4; ++c2) {
        wa[c2][0] = ald64(rhb + base0 + c2 * 8);
        wa[c2][1] = ald64(rhb + base0 + c2 * 8 + 1);
        wb[c2][0] = ald64(rhb + base1 + c2 * 8);
        wb[c2][1] = ald64(rhb + base1 + c2 * 8 + 1);
      }
      floatx4 acc[2] = {};
#pragma unroll
      for (int c2 = 0; c2 < 4; ++c2) {
        union { uint4 u; bf16x8 v; } fa, fb;
        fa.u = make_uint4((uint)wa[c2][0], (uint)(wa[c2][0] >> 32),
                          (uint)wa[c2][1], (uint)(wa[c2][1] >> 32));
        fb.u = make_uint4((uint)wb[c2][0], (uint)(wb[c2][0] >> 32),
                          (uint)wb[c2][1], (uint)(wb[c2][1] >> 32));
        const int kb = w * 128 + c2 * 32 + kq * 8;
        bf16x8 bb = *reinterpret_cast<const bf16x8*>(Wc + mr * WS + kb);
        acc[0] = __builtin_amdgcn_mfma_f32_16x16x32_bf16(fa.v, bb, acc[0], 0, 0, 0);
        acc[1] = __builtin_amdgcn_mfma_f32_16x16x32_bf16(fb.v, bb, acc[1], 0, 0, 0);
      }
#pragma unroll
      for (int ai = 0; ai < 2; ++ai)
#pragma unroll
        for (int r = 0; r < 4; ++r)
          red[w * 1056 + (ai * 16 + kq * 4 + r) * 33 + mr] = acc[ai][r];
      __syncthreads();
      {
        int n = tid >> 4, col = tid & 15;
        float s = 0.f;
#pragma unroll
        for (int w8 = 0; w8 < 8; ++w8) s += red[w8 * 1056 + n * 33 + col];
        float hc = tanhf_(s + (float)gcraw);
        float hp = hp_s[n * 16 + col];
        float uu = u_s[n * 16 + col];
        float hn = hp + uu * (hc - hp);
        hp_s[n * 16 + col] = hn;
        hn_keep = hn;
        u64 p4 = pack4(hn);
        if (!(col & 3))
          ast64(ht_w + (size_t)((e + 1u) & 1) * 8192 + n * 256 + b * 4 + (col >> 2), p4);
      }
      __syncthreads();                            // drains vmcnt: ht data at LIC
      if (tid == 0) {
        asm volatile("s_waitcnt vmcnt(0)" ::: "memory");
        ast64(fht + b * 16, (u64)(e + 1u));
      }
      // htseq/otail stores AFTER flag publish — their drain overlaps next phase's poll
      {
        int n = tid >> 4, col = tid & 15;
        htseq[(size_t)(t * 32 + n) * 1024 + b * 16 + col] = (__bf16)hn_keep;
        if (t == 511) otail[n * 1024 + b * 16 + col] = hn_keep;
      }
    }
  }
}

// ---------------- launch ----------------

extern "C" void kernel_launch(void* const* d_in, const int* in_sizes, int n_in,
                              void* d_out, int out_size, void* d_ws, size_t ws_size,
                              hipStream_t stream) {
  const float* x = (const float*)d_in[0];
  const float* state = (const float*)d_in[1];
  const float* weight = (const float*)d_in[2];
  const float* bias = (const float*)d_in[3];
  float* out = (float*)d_out;
  char* ws = (char*)d_ws;

  __bf16* gates  = (__bf16*)(ws + OFF_GATES);
  __bf16* xb     = (__bf16*)(ws + OFF_XB);
  __bf16* htseq  = (__bf16*)(ws + OFF_HTSEQ);
  __bf16* whtg_t = (__bf16*)(ws + OFF_WHTGT);
  __bf16* whtc_t = (__bf16*)(ws + OFF_WHTCT);
  __bf16* wxtt   = (__bf16*)(ws + OFF_WXTT);
  __bf16* whdt   = (__bf16*)(ws + OFF_WHDT);
  __bf16* wxd1t  = (__bf16*)(ws + OFF_WXD1T);
  __bf16* wxd2t  = (__bf16*)(ws + OFF_WXD2T);
  u64*    comm   = (u64*)(ws + OFF_COMM);
  u64*    ht_w   = comm;                 // 2 x 8192
  u64*    rh_w   = comm + 16384;         // 2 x 8192
  u64*    fht    = comm + 32768;         // 64 x 16
  u64*    frh    = comm + 33792;         // 64 x 16

  // prep: x -> bf16 t-major, weight blocks -> bf16 B^T
  hipLaunchKernelGGL(convert_x, dim3(16384), dim3(256), 0, stream, (const float4*)x, xb);
  hipLaunchKernelGGL(transpose_conv, dim3(96, 32), dim3(256), 0, stream, weight, wxtt);
  hipLaunchKernelGGL(transpose_conv, dim3(64, 32), dim3(256), 0, stream, weight + 3072, wxd1t);
  hipLaunchKernelGGL(transpose_conv, dim3(32, 32), dim3(256), 0, stream, weight + 5120, wxd2t);
  hipLaunchKernelGGL(transpose_conv, dim3(96, 32), dim3(256), 0, stream,
                     weight + (size_t)1024 * WLD + 3072, whdt);
  hipLaunchKernelGGL(transpose_conv, dim3(64, 32), dim3(256), 0, stream,
                     weight + (size_t)1024 * WLD, whtg_t);
  hipLaunchKernelGGL(transpose_conv, dim3(32, 32), dim3(256), 0, stream,
                     weight + (size_t)1024 * WLD + 2048, whtc_t);

  // gates = x @ Wxt + bias[:3H]   (t-major rows)
  hipLaunchKernelGGL((gemm_bt<0>), dim3(24, 128), dim3(256), 0, stream,
                     xb, 1024, wxtt, bias, gates, (const float*)nullptr, (float*)nullptr, 3072);

  // zero flags (overlay wxtt — must follow gemm<0>, precede recur)
  hipLaunchKernelGGL(zero_flags, dim3(8), dim3(256), 0, stream, fht);

  // recurrence (cooperative, 64 WGs x 512 threads, flag-gated dataflow)
  {
    (void)hipFuncSetAttribute(reinterpret_cast<const void*>(recur_kernel),
                              hipFuncAttributeMaxDynamicSharedMemorySize, SMEM_BYTES);
    const __bf16* gatesc = gates;
    float* otail = out + 16777216;
    void* args[10];
    args[0] = (void*)&gatesc; args[1] = (void*)&state;  args[2] = (void*)&whtg_t;
    args[3] = (void*)&whtc_t; args[4] = (void*)&ht_w;   args[5] = (void*)&rh_w;
    args[6] = (void*)&fht;    args[7] = (void*)&frh;    args[8] = (void*)&htseq;
    args[9] = (void*)&otail;
    hipLaunchCooperativeKernel(recur_kernel, dim3(64), dim3(512), args, SMEM_BYTES, stream);
  }

  // gd = ht_seq @ Whd + bias[3H:]  (into gates buffer)
  hipLaunchKernelGGL((gemm_bt<1>), dim3(24, 128), dim3(256), 0, stream,
                     htseq, 1024, whdt, bias + 3072, gates, (const float*)nullptr,
                     (float*)nullptr, 3072);
  // g2 = sigmoid(gd[:, :2D] + x @ Wxd[:, :2D]); ud/rx in-place
  hipLaunchKernelGGL((gemm_bt<2>), dim3(16, 128), dim3(256), 0, stream,
                     xb, 1024, wxd1t, bias, gates, x, (float*)nullptr, 2048);
  // hcd = tanh(gd[:, 2D:] + rx @ Wxd[:, 2D:]); h = x + ud*(hcd - x)
  hipLaunchKernelGGL((gemm_bt<3>), dim3(8, 128), dim3(256), 0, stream,
                     gates + 1024, 3072, wxd2t, bias, gates, x, out, 1024);
}

// Round 4
// 5708.519 us; speedup vs baseline: 1.6854x; 1.0929x over previous
//
#include <hip/hip_runtime.h>
#include <cstdint>
#include <cstddef>

typedef unsigned int uint;
typedef unsigned short ushort;
typedef unsigned long long u64;
typedef __attribute__((ext_vector_type(8))) __bf16 bf16x8;
typedef __attribute__((ext_vector_type(4))) __bf16 bf16x4v;
typedef __attribute__((ext_vector_type(4))) float floatx4;

#define WLD 6144      // weight row stride = 3*(D+H)

// ---- workspace layout (bytes). Row convention for xb/gates/htseq: r = t*32 + n (t-major).
static const size_t OFF_GATES = 0;              // bf16 16384x3072
static const size_t OFF_XB    = 100663296;      // bf16 16384x1024
static const size_t OFF_HTSEQ = 134217728;      // bf16 16384x1024
// whtg_t/whtc_t overlay the htseq region: consumed (into LDS) before any htseq write.
static const size_t OFF_WHTGT = OFF_HTSEQ;              // bf16 2048x1024
static const size_t OFF_WHTCT = OFF_HTSEQ + 4194304;    // bf16 1024x1024
static const size_t OFF_WXTT  = 167772160;      // bf16 3072x1024 (B^T)
// Comm region overlays wxtt (dead after gemm<0>, which precedes zero_flags + recur):
//   ht data : u64[2][8192]  (parity-double-buffered 32x1024 bf16, 4 bf16/u64, 256 u64/row)
//   rh data : u64[2][8192]
//   fht     : u64[512*16]   (per-producer-WAVE flags, 128B apart)
//   frh     : u64[512*16]
static const size_t OFF_COMM  = OFF_WXTT;
static const size_t OFF_WHDT  = 174063616;      // bf16 3072x1024
static const size_t OFF_WXD1T = 180355072;      // bf16 2048x1024
static const size_t OFF_WXD2T = 184549376;      // bf16 1024x1024

__device__ __forceinline__ float sigmoidf_(float x) { return 1.f / (1.f + __expf(-x)); }
__device__ __forceinline__ float tanhf_(float x) { float e = __expf(2.f * x); return 1.f - 2.f / (e + 1.f); }

// agent-scope relaxed atomics: operate at the device coherence point.
__device__ __forceinline__ u64 ald64(const u64* p) {
  return __hip_atomic_load(p, __ATOMIC_RELAXED, __HIP_MEMORY_SCOPE_AGENT);
}
__device__ __forceinline__ void ast64(u64* p, u64 v) {
  __hip_atomic_store(p, v, __ATOMIC_RELAXED, __HIP_MEMORY_SCOPE_AGENT);
}
__device__ __forceinline__ ushort bfb(float v) {
  union { __bf16 b; ushort u; } t; t.b = (__bf16)v; return t.u;
}
// pack 4 bf16 (cols c..c+3 within a 16-lane group) into one u64 (valid in lanes c%4==0)
__device__ __forceinline__ u64 pack4(float v) {
  ushort h = bfb(v);
  uint p2 = (uint)h | ((uint)(ushort)__shfl_xor((int)h, 1) << 16);
  u64 p4 = (u64)p2 | ((u64)(uint)__shfl_xor((int)p2, 2) << 32);
  return p4;
}
// 16B coherence-point load (bypasses L1/L2): reads what agent-atomic stores published.
union U4 { uint4 u; bf16x8 v; };
__device__ __forceinline__ void ld16_cp(U4* dst, const u64* p) {
  asm volatile("global_load_dwordx4 %0, %1, off sc0 sc1" : "=v"(dst->u) : "v"(p));
}

// ---------------- prep kernels ----------------

// x [n][t][1024] fp32 -> xb bf16 rows r=t*32+n.
__global__ __launch_bounds__(256) void convert_x(const float4* __restrict__ x4,
                                                 __bf16* __restrict__ xb) {
  const int s = blockIdx.x;              // source row n*512+t
  const int n = s >> 9, t = s & 511;
  const int d = (t << 5) | n;            // dest row t*32+n
  float4 v = x4[(size_t)s * 256 + threadIdx.x];
  bf16x4v o = { (__bf16)v.x, (__bf16)v.y, (__bf16)v.z, (__bf16)v.w };
  *reinterpret_cast<bf16x4v*>(xb + (size_t)d * 1024 + threadIdx.x * 4) = o;
}

// zero the flag region (16384 u64) at the coherence point.
__global__ __launch_bounds__(256) void zero_flags(u64* __restrict__ f) {
  ast64(f + (size_t)blockIdx.x * 256 + threadIdx.x, 0ull);
}

// src: fp32 block, row stride WLD, 1024 rows (k), gridDim.x*32 cols. dst: bf16 [c][k].
__global__ __launch_bounds__(256) void transpose_conv(const float* __restrict__ src,
                                                      __bf16* __restrict__ dst) {
  __shared__ float t[32][33];
  const int ct = blockIdx.x, kt = blockIdx.y;
  const int j = threadIdx.x & 31, ig = threadIdx.x >> 5;
#pragma unroll
  for (int ii = 0; ii < 4; ++ii) {
    int i = ig * 4 + ii;
    t[i][j] = src[(size_t)(kt * 32 + i) * WLD + ct * 32 + j];
  }
  __syncthreads();
#pragma unroll
  for (int ii = 0; ii < 4; ++ii) {
    int cc = ig * 4 + ii;
    dst[(size_t)(ct * 32 + cc) * 1024 + kt * 32 + j] = (__bf16)t[j][cc];
  }
}

// ---------------- MFMA GEMM (A row-major bf16 t-major rows, B^T bf16 [n][k]) ----------------
template <int MODE>
__global__ __launch_bounds__(256) void gemm_bt(const __bf16* __restrict__ A, int lda,
                                               const __bf16* __restrict__ BT,
                                               const float* __restrict__ bias,
                                               __bf16* __restrict__ gbuf,
                                               const float* __restrict__ xf,
                                               float* __restrict__ hout, int ncols) {
  __shared__ __bf16 As[128][48];
  __shared__ __bf16 Bs[128][48];
  const int tid = threadIdx.x;
  const int lane = tid & 63, wave = tid >> 6;
  const int tm = blockIdx.y, tn = blockIdx.x;
  const int wm = (wave & 1) * 64, wn = (wave >> 1) * 64;
  floatx4 acc[4][4] = {};
  const int c = tid & 3, r0 = tid >> 2;
  const size_t arow = (size_t)tm * 128;
  const size_t brow = (size_t)tn * 128;

  for (int kk = 0; kk < 1024; kk += 32) {
    *reinterpret_cast<uint4*>(&As[r0][c * 8]) =
        *reinterpret_cast<const uint4*>(A + (arow + r0) * (size_t)lda + kk + c * 8);
    *reinterpret_cast<uint4*>(&As[r0 + 64][c * 8]) =
        *reinterpret_cast<const uint4*>(A + (arow + r0 + 64) * (size_t)lda + kk + c * 8);
    *reinterpret_cast<uint4*>(&Bs[r0][c * 8]) =
        *reinterpret_cast<const uint4*>(BT + (brow + r0) * 1024 + kk + c * 8);
    *reinterpret_cast<uint4*>(&Bs[r0 + 64][c * 8]) =
        *reinterpret_cast<const uint4*>(BT + (brow + r0 + 64) * 1024 + kk + c * 8);
    __syncthreads();
    const int mr = lane & 15, kg = (lane >> 4) * 8;
    bf16x8 af[4], bfr[4];
#pragma unroll
    for (int f = 0; f < 4; ++f) af[f] = *reinterpret_cast<const bf16x8*>(&As[wm + f * 16 + mr][kg]);
#pragma unroll
    for (int f = 0; f < 4; ++f) bfr[f] = *reinterpret_cast<const bf16x8*>(&Bs[wn + f * 16 + mr][kg]);
#pragma unroll
    for (int fi = 0; fi < 4; ++fi)
#pragma unroll
      for (int fj = 0; fj < 4; ++fj)
        acc[fi][fj] = __builtin_amdgcn_mfma_f32_16x16x32_bf16(af[fi], bfr[fj], acc[fi][fj], 0, 0, 0);
    __syncthreads();
  }

#pragma unroll
  for (int fi = 0; fi < 4; ++fi)
#pragma unroll
    for (int fj = 0; fj < 4; ++fj) {
      const int row0 = tm * 128 + wm + fi * 16 + (lane >> 4) * 4;
      const int col = tn * 128 + wn + fj * 16 + (lane & 15);
#pragma unroll
      for (int r = 0; r < 4; ++r) {
        const size_t row = (size_t)(row0 + r);
        float v = acc[fi][fj][r];
        if (MODE == 0 || MODE == 1) {
          gbuf[row * 3072 + col] = (__bf16)(v + bias[col]);
        } else if (MODE == 2) {
          float g = sigmoidf_(v + (float)gbuf[row * 3072 + col]);
          const size_t xrow = (size_t)(row & 31) * 512 + (row >> 5);
          if (col < 1024)
            gbuf[row * 3072 + col] = (__bf16)g;                                   // ud
          else
            gbuf[row * 3072 + col] = (__bf16)(g * xf[xrow * 1024 + (col - 1024)]); // rd*x
        } else {
          float hcd = tanhf_(v + (float)gbuf[row * 3072 + 2048 + col]);
          float ud = (float)gbuf[row * 3072 + col];
          const size_t xrow = (size_t)(row & 31) * 512 + (row >> 5);
          float xv = xf[xrow * 1024 + col];
          hout[xrow * 1024 + col] = xv + ud * (hcd - xv);
        }
      }
    }
}

// ---------------- persistent recurrence (per-wave flags, wide bypass reads) ----------------
// 64 WGs x 512 threads (8 waves). Wave w of WG b:
//   - consumes K-slice [w*128, w*128+128) of the broadcast (ht or r*ht)
//   - produces rows 4w..4w+3 (all 16 own cols) of the next broadcast slice
// Producer wave: data ast64 stores -> own s_waitcnt vmcnt(0) -> own flag (no WG barrier).
// Consumer wave: 64 lanes poll the 64 producer-wave flags (8 WGs x 8 waves) covering
// its rows+K-range, then 16B sc0sc1 loads (bypass L1/L2 -> coherence point).
// u and hp live in REGISTERS (same thread computes and consumes them).
// red scratch is double-buffered (A: 32 cols, B: 16 cols) -> one barrier per phase.
// Parity reuse safe: epoch-e reads retire (vmcnt drain) before epoch-e flag; writes of
// epoch e+2 are gated (transitively) on all epoch-e+1 flags.
#define SMEM_BYTES 150272
#define WS 1032
__global__ __launch_bounds__(512) void recur_kernel(
    const __bf16* __restrict__ gates, const float* __restrict__ state,
    const __bf16* __restrict__ whtg_t, const __bf16* __restrict__ whtc_t,
    u64* __restrict__ ht_w, u64* __restrict__ rh_w,
    u64* __restrict__ fht, u64* __restrict__ frh,
    __bf16* __restrict__ htseq, float* __restrict__ otail) {
  extern __shared__ char smem[];
  __bf16* Wg   = (__bf16*)smem;                   // [32][WS]   66048 B
  __bf16* Wc   = (__bf16*)(smem + 66048);         // [16][WS]   33024 B
  float*  redA = (float*)(smem + 99072);          // [8][32][33] 33792 B
  float*  redB = (float*)(smem + 132864);         // [8][32][17] 17408 B

  const int b = blockIdx.x, tid = threadIdx.x;
  const int lane = tid & 63, w = tid >> 6;       // wave w owns K range [w*128, w*128+128)
  const int mr = lane & 15, kq = lane >> 4;
  const int n = 4 * w + kq;                      // epilogue row owned by this lane
  const int c = mr;                              // epilogue col (0..15) within WG's 16
  // u64 base indices into a 32x1024 bf16 buffer (256 u64 per row)
  const int base0 = mr * 256 + w * 32 + kq * 2;         // + c2*8
  const int base1 = (16 + mr) * 256 + w * 32 + kq * 2;  // + c2*8
  // poll address: producer WG w*8+(lane>>3), wave lane&7
  const u64* fpA = fht + ((size_t)(w * 8 + (lane >> 3)) * 8 + (lane & 7)) * 16;
  const u64* fpB = frh + ((size_t)(w * 8 + (lane >> 3)) * 8 + (lane & 7)) * 16;

  // ---- init: weights -> LDS ----
  for (int idx = tid; idx < 4096; idx += 512) {
    int row = idx >> 7, seg = idx & 127;
    int src = (row < 16) ? (b * 16 + row) : (1024 + b * 16 + row - 16);
    *reinterpret_cast<uint4*>(Wg + row * WS + seg * 8) =
        *reinterpret_cast<const uint4*>(whtg_t + (size_t)src * 1024 + seg * 8);
  }
  for (int idx = tid; idx < 2048; idx += 512) {
    int row = idx >> 7, seg = idx & 127;
    *reinterpret_cast<uint4*>(Wc + row * WS + seg * 8) =
        *reinterpret_cast<const uint4*>(whtc_t + (size_t)(b * 16 + row) * 1024 + seg * 8);
  }
  // ---- init: state -> hp register, publish ht@1 (parity 1) ----
  float hp_reg = state[n * 1024 + b * 16 + c];
  float u_reg = 0.f;
  {
    u64 p4 = pack4(hp_reg);
    if (!(lane & 3)) ast64(ht_w + 8192 + n * 256 + b * 4 + (c >> 2), p4);
  }
  __syncthreads();                                // drains all waves' stores, weights ready
  if (lane == 0) ast64(fht + (size_t)(b * 8 + w) * 16, 1ull);

  for (int t = 0; t < 512; ++t) {
    const uint e = (uint)t + 1u;
    const u64* htb = ht_w + (size_t)(e & 1) * 8192;
    u64*       rhb = rh_w + (size_t)(e & 1) * 8192;
    // ================= phase A: gg = sigmoid(gates + ht @ Whtg) =================
    {
      // prefetch gates (latency hides under the poll)
      __bf16 graw_u = gates[(size_t)(t * 32 + n) * 3072 + b * 16 + c];
      __bf16 graw_r = gates[(size_t)(t * 32 + n) * 3072 + 1024 + b * 16 + c];
      // wait for the 64 producer waves covering this wave's K range
      while (!__all(ald64(fpA) >= (u64)e)) {}
      asm volatile("" ::: "memory");
      // 16B bypass loads (guaranteed valid)
      U4 wa[4], wb[4];
#pragma unroll
      for (int c2 = 0; c2 < 4; ++c2) {
        ld16_cp(&wa[c2], htb + base0 + c2 * 8);
        ld16_cp(&wb[c2], htb + base1 + c2 * 8);
      }
      asm volatile("s_waitcnt vmcnt(0)" ::: "memory");
      __builtin_amdgcn_sched_barrier(0);
      floatx4 acc[2][2] = {};
#pragma unroll
      for (int c2 = 0; c2 < 4; ++c2) {
        const int kb = w * 128 + c2 * 32 + kq * 8;
        bf16x8 b0 = *reinterpret_cast<const bf16x8*>(Wg + mr * WS + kb);
        bf16x8 b1 = *reinterpret_cast<const bf16x8*>(Wg + (16 + mr) * WS + kb);
        acc[0][0] = __builtin_amdgcn_mfma_f32_16x16x32_bf16(wa[c2].v, b0, acc[0][0], 0, 0, 0);
        acc[0][1] = __builtin_amdgcn_mfma_f32_16x16x32_bf16(wa[c2].v, b1, acc[0][1], 0, 0, 0);
        acc[1][0] = __builtin_amdgcn_mfma_f32_16x16x32_bf16(wb[c2].v, b0, acc[1][0], 0, 0, 0);
        acc[1][1] = __builtin_amdgcn_mfma_f32_16x16x32_bf16(wb[c2].v, b1, acc[1][1], 0, 0, 0);
      }
#pragma unroll
      for (int ai = 0; ai < 2; ++ai)
#pragma unroll
        for (int cj = 0; cj < 2; ++cj)
#pragma unroll
          for (int r = 0; r < 4; ++r)
            redA[w * 1056 + (ai * 16 + kq * 4 + r) * 33 + cj * 16 + mr] = acc[ai][cj][r];
      __syncthreads();
      // reduce over 8 waves; epilogue in registers; publish r*ht slice (own rows)
      {
        float s1 = 0.f, s2 = 0.f;
#pragma unroll
        for (int w8 = 0; w8 < 8; ++w8) {
          s1 += redA[w8 * 1056 + n * 33 + c];
          s2 += redA[w8 * 1056 + n * 33 + 16 + c];
        }
        u_reg = sigmoidf_(s1 + (float)graw_u);
        float gg_r = sigmoidf_(s2 + (float)graw_r);
        float pub = gg_r * hp_reg;
        u64 p4 = pack4(pub);
        if (!(lane & 3)) ast64(rhb + n * 256 + b * 4 + (c >> 2), p4);
      }
      asm volatile("s_waitcnt vmcnt(0)" ::: "memory");   // own stores at coherence point
      if (lane == 0) ast64(frh + (size_t)(b * 8 + w) * 16, (u64)e);
    }
    // ================= phase B: hc = tanh(gates_c + (r*ht) @ Whtc); update =================
    {
      __bf16 gcraw = gates[(size_t)(t * 32 + n) * 3072 + 2048 + b * 16 + c];
      while (!__all(ald64(fpB) >= (u64)e)) {}
      asm volatile("" ::: "memory");
      U4 wa[4], wb[4];
#pragma unroll
      for (int c2 = 0; c2 < 4; ++c2) {
        ld16_cp(&wa[c2], rhb + base0 + c2 * 8);
        ld16_cp(&wb[c2], rhb + base1 + c2 * 8);
      }
      asm volatile("s_waitcnt vmcnt(0)" ::: "memory");
      __builtin_amdgcn_sched_barrier(0);
      floatx4 acc[2] = {};
#pragma unroll
      for (int c2 = 0; c2 < 4; ++c2) {
        const int kb = w * 128 + c2 * 32 + kq * 8;
        bf16x8 bb = *reinterpret_cast<const bf16x8*>(Wc + mr * WS + kb);
        acc[0] = __builtin_amdgcn_mfma_f32_16x16x32_bf16(wa[c2].v, bb, acc[0], 0, 0, 0);
        acc[1] = __builtin_amdgcn_mfma_f32_16x16x32_bf16(wb[c2].v, bb, acc[1], 0, 0, 0);
      }
#pragma unroll
      for (int ai = 0; ai < 2; ++ai)
#pragma unroll
        for (int r = 0; r < 4; ++r)
          redB[w * 544 + (ai * 16 + kq * 4 + r) * 17 + mr] = acc[ai][r];
      __syncthreads();
      {
        float s = 0.f;
#pragma unroll
        for (int w8 = 0; w8 < 8; ++w8) s += redB[w8 * 544 + n * 17 + c];
        float hc = tanhf_(s + (float)gcraw);
        float hn = hp_reg + u_reg * (hc - hp_reg);
        hp_reg = hn;
        u64 p4 = pack4(hn);
        if (!(lane & 3))
          ast64(ht_w + (size_t)((e + 1u) & 1) * 8192 + n * 256 + b * 4 + (c >> 2), p4);
        asm volatile("s_waitcnt vmcnt(0)" ::: "memory"); // own ht stores at coherence point
        if (lane == 0) ast64(fht + (size_t)(b * 8 + w) * 16, (u64)(e + 1u));
        // htseq/otail after flag publish — off the critical path
        htseq[(size_t)(t * 32 + n) * 1024 + b * 16 + c] = (__bf16)hn;
        if (t == 511) otail[n * 1024 + b * 16 + c] = hn;
      }
    }
  }
}

// ---------------- launch ----------------

extern "C" void kernel_launch(void* const* d_in, const int* in_sizes, int n_in,
                              void* d_out, int out_size, void* d_ws, size_t ws_size,
                              hipStream_t stream) {
  const float* x = (const float*)d_in[0];
  const float* state = (const float*)d_in[1];
  const float* weight = (const float*)d_in[2];
  const float* bias = (const float*)d_in[3];
  float* out = (float*)d_out;
  char* ws = (char*)d_ws;

  __bf16* gates  = (__bf16*)(ws + OFF_GATES);
  __bf16* xb     = (__bf16*)(ws + OFF_XB);
  __bf16* htseq  = (__bf16*)(ws + OFF_HTSEQ);
  __bf16* whtg_t = (__bf16*)(ws + OFF_WHTGT);
  __bf16* whtc_t = (__bf16*)(ws + OFF_WHTCT);
  __bf16* wxtt   = (__bf16*)(ws + OFF_WXTT);
  __bf16* whdt   = (__bf16*)(ws + OFF_WHDT);
  __bf16* wxd1t  = (__bf16*)(ws + OFF_WXD1T);
  __bf16* wxd2t  = (__bf16*)(ws + OFF_WXD2T);
  u64*    comm   = (u64*)(ws + OFF_COMM);
  u64*    ht_w   = comm;                 // 2 x 8192
  u64*    rh_w   = comm + 16384;         // 2 x 8192
  u64*    fht    = comm + 32768;         // 512 x 16
  u64*    frh    = comm + 40960;         // 512 x 16

  // prep: x -> bf16 t-major, weight blocks -> bf16 B^T
  hipLaunchKernelGGL(convert_x, dim3(16384), dim3(256), 0, stream, (const float4*)x, xb);
  hipLaunchKernelGGL(transpose_conv, dim3(96, 32), dim3(256), 0, stream, weight, wxtt);
  hipLaunchKernelGGL(transpose_conv, dim3(64, 32), dim3(256), 0, stream, weight + 3072, wxd1t);
  hipLaunchKernelGGL(transpose_conv, dim3(32, 32), dim3(256), 0, stream, weight + 5120, wxd2t);
  hipLaunchKernelGGL(transpose_conv, dim3(96, 32), dim3(256), 0, stream,
                     weight + (size_t)1024 * WLD + 3072, whdt);
  hipLaunchKernelGGL(transpose_conv, dim3(64, 32), dim3(256), 0, stream,
                     weight + (size_t)1024 * WLD, whtg_t);
  hipLaunchKernelGGL(transpose_conv, dim3(32, 32), dim3(256), 0, stream,
                     weight + (size_t)1024 * WLD + 2048, whtc_t);

  // gates = x @ Wxt + bias[:3H]   (t-major rows)
  hipLaunchKernelGGL((gemm_bt<0>), dim3(24, 128), dim3(256), 0, stream,
                     xb, 1024, wxtt, bias, gates, (const float*)nullptr, (float*)nullptr, 3072);

  // zero flags (overlay wxtt — must follow gemm<0>, precede recur)
  hipLaunchKernelGGL(zero_flags, dim3(64), dim3(256), 0, stream, fht);

  // recurrence (cooperative, 64 WGs x 512 threads, per-wave flag dataflow)
  {
    (void)hipFuncSetAttribute(reinterpret_cast<const void*>(recur_kernel),
                              hipFuncAttributeMaxDynamicSharedMemorySize, SMEM_BYTES);
    const __bf16* gatesc = gates;
    float* otail = out + 16777216;
    void* args[10];
    args[0] = (void*)&gatesc; args[1] = (void*)&state;  args[2] = (void*)&whtg_t;
    args[3] = (void*)&whtc_t; args[4] = (void*)&ht_w;   args[5] = (void*)&rh_w;
    args[6] = (void*)&fht;    args[7] = (void*)&frh;    args[8] = (void*)&htseq;
    args[9] = (void*)&otail;
    hipLaunchCooperativeKernel(recur_kernel, dim3(64), dim3(512), args, SMEM_BYTES, stream);
  }

  // gd = ht_seq @ Whd + bias[3H:]  (into gates buffer)
  hipLaunchKernelGGL((gemm_bt<1>), dim3(24, 128), dim3(256), 0, stream,
                     htseq, 1024, whdt, bias + 3072, gates, (const float*)nullptr,
                     (float*)nullptr, 3072);
  // g2 = sigmoid(gd[:, :2D] + x @ Wxd[:, :2D]); ud/rx in-place
  hipLaunchKernelGGL((gemm_bt<2>), dim3(16, 128), dim3(256), 0, stream,
                     xb, 1024, wxd1t, bias, gates, x, (float*)nullptr, 2048);
  // hcd = tanh(gd[:, 2D:] + rx @ Wxd[:, 2D:]); h = x + ud*(hcd - x)
  hipLaunchKernelGGL((gemm_bt<3>), dim3(8, 128), dim3(256), 0, stream,
                     gates + 1024, 3072, wxd2t, bias, gates, x, out, 1024);
}